// Round 2
// baseline (487.147 us; speedup 1.0000x reference)
//
#include <hip/hip_runtime.h>

#define B_ 512
#define T_ 512
#define F_ 128
#define H_ 32
#define C_ 6
#define K4 128   // 4*H

// ---------------------------------------------------------------------------
// Kernel 1: xz[t][b][j][g] = x[b,t,:] @ Wx[:, g*32+j] + bias[g*32+j]
// (gate-minor permuted column layout so k_lstm loads one float4 per lane/step)
// Also: mask[t][b] = any(x[b,t,:] != 0.0f)   (float compare: -0.0 counts as 0)
// grid: (B/64, T), block: 128 threads. Block tile 64 rows x 128 cols,
// thread tile 8 rows x 8 cols, K staged in 4 chunks of 32.
// ---------------------------------------------------------------------------
__global__ __launch_bounds__(128) void k_xz(
    const float* __restrict__ x, const float* __restrict__ Wx,
    const float* __restrict__ bias, float* __restrict__ xz,
    float* __restrict__ mask)
{
  __shared__ float xl[64 * 128];   // 32 KB: 64 rows of x
  __shared__ float wl[32 * 128];   // 16 KB: K-chunk of Wx, column-permuted
  const int tid = threadIdx.x;
  const int t  = blockIdx.y;
  const int b0 = blockIdx.x * 64;
  const int cg = tid & 15;   // col group: output cols kp = cg*8 .. cg*8+7
  const int rg = tid >> 4;   // row group: rows rg*8 .. rg*8+7

  // stage x rows
  for (int i = tid; i < 64 * 32; i += 128) {
    const int r = i >> 5, fq = i & 31;
    float4 v = *(const float4*)(x + (size_t)(b0 + r) * (T_ * F_) + (size_t)t * F_ + fq * 4);
    *(float4*)(xl + r * 128 + fq * 4) = v;
  }
  __syncthreads();

  // mask for the 64 rows (one thread per row)
  if (tid < 64) {
    const float4* row = (const float4*)(xl + tid * 128);
    bool nz = false;
#pragma unroll
    for (int q = 0; q < 32; ++q) {
      float4 v = row[q];
      nz = nz || (v.x != 0.f) || (v.y != 0.f) || (v.z != 0.f) || (v.w != 0.f);
    }
    mask[(size_t)t * B_ + b0 + tid] = nz ? 1.f : 0.f;
  }

  // bias for this thread's 8 output cols (permuted: kp = j*4+g -> src g*32+j)
  float bb[8];
#pragma unroll
  for (int u = 0; u < 8; ++u) {
    const int kp = cg * 8 + u;
    bb[u] = bias[(kp & 3) * 32 + (kp >> 2)];
  }

  float acc[8][8];
#pragma unroll
  for (int r = 0; r < 8; ++r)
#pragma unroll
    for (int u = 0; u < 8; ++u) acc[r][u] = 0.f;

  for (int ch = 0; ch < 4; ++ch) {
    __syncthreads();   // protect wl reuse
    // stage W chunk, permuted: wl[f][(c&31)*4 + (c>>5)] = Wx[ch*32+f][c]
    for (int i = tid; i < 32 * 32; i += 128) {
      const int f = i >> 5, cq = i & 31;
      float4 v = *(const float4*)(Wx + (size_t)(ch * 32 + f) * K4 + cq * 4);
      const int c0 = cq * 4;
      wl[f * 128 + ((c0    ) & 31) * 4 + ((c0    ) >> 5)] = v.x;
      wl[f * 128 + ((c0 + 1) & 31) * 4 + ((c0 + 1) >> 5)] = v.y;
      wl[f * 128 + ((c0 + 2) & 31) * 4 + ((c0 + 2) >> 5)] = v.z;
      wl[f * 128 + ((c0 + 3) & 31) * 4 + ((c0 + 3) >> 5)] = v.w;
    }
    __syncthreads();

#pragma unroll
    for (int fq = 0; fq < 8; ++fq) {
      float4 xv[8];
#pragma unroll
      for (int r = 0; r < 8; ++r)
        xv[r] = *(const float4*)(xl + (rg * 8 + r) * 128 + ch * 32 + fq * 4);
#pragma unroll
      for (int ff = 0; ff < 4; ++ff) {
        const float* wr = wl + (fq * 4 + ff) * 128 + cg * 8;
        const float4 wa = *(const float4*)(wr);
        const float4 wb = *(const float4*)(wr + 4);
#pragma unroll
        for (int r = 0; r < 8; ++r) {
          const float xs = (ff == 0) ? xv[r].x : (ff == 1) ? xv[r].y
                         : (ff == 2) ? xv[r].z : xv[r].w;
          acc[r][0] += xs * wa.x;  acc[r][1] += xs * wa.y;
          acc[r][2] += xs * wa.z;  acc[r][3] += xs * wa.w;
          acc[r][4] += xs * wb.x;  acc[r][5] += xs * wb.y;
          acc[r][6] += xs * wb.z;  acc[r][7] += xs * wb.w;
        }
      }
    }
  }

  // store: xz[(t*B + row)*128 + cg*8 .. +7]
#pragma unroll
  for (int r = 0; r < 8; ++r) {
    float* op = xz + ((size_t)t * B_ + b0 + rg * 8 + r) * 128 + cg * 8;
    float4 o0 = { acc[r][0] + bb[0], acc[r][1] + bb[1], acc[r][2] + bb[2], acc[r][3] + bb[3] };
    float4 o1 = { acc[r][4] + bb[4], acc[r][5] + bb[5], acc[r][6] + bb[6], acc[r][7] + bb[7] };
    *(float4*)(op)     = o0;
    *(float4*)(op + 4) = o1;
  }
}

// ---------------------------------------------------------------------------
// Kernel 2: sequential LSTM scan + FC + softmax.
// grid: 256 blocks x 64 threads. One wave = 2 batch rows (lanes 0-31 / 32-63),
// lane j owns gate column j of all 4 gates; h replicated in registers,
// Wh column-permuted in 128 registers; per-step LDS broadcast of new h.
// ---------------------------------------------------------------------------
__device__ __forceinline__ float sigmf(float xx) {
  return __builtin_amdgcn_rcpf(1.f + __expf(-xx));
}
__device__ __forceinline__ float tanhf_(float xx) {
  return __builtin_amdgcn_rcpf(1.f + __expf(-2.f * xx)) * 2.f - 1.f;
}

__global__ __launch_bounds__(64) void k_lstm(
    const float* __restrict__ xz, const float* __restrict__ mask,
    const float* __restrict__ Wh, const float* __restrict__ Wfc,
    const float* __restrict__ bfc, float* __restrict__ out)
{
  const int lane = threadIdx.x;
  const int half = lane >> 5;
  const int j = lane & 31;
  const int b = blockIdx.x * 2 + half;

  // Wh permuted into registers: Whr[f][g] = Wh[f][g*32+j]
  float Whr[32][4];
#pragma unroll
  for (int f = 0; f < 32; ++f)
#pragma unroll
    for (int g = 0; g < 4; ++g)
      Whr[f][g] = Wh[f * 128 + g * 32 + j];

  float hr[32];
#pragma unroll
  for (int f = 0; f < 32; ++f) hr[f] = 0.f;
  float cj = 0.f, hj = 0.f;

  __shared__ __align__(16) float hs[2][32];

  const float* xp = xz + (size_t)b * 128 + (size_t)j * 4;  // + t*B*128 per step
  float4 xq = *(const float4*)(xp);
  float  m  = mask[b];

  for (int t = 0; t < T_; ++t) {
    float4 xq_n = xq;
    float  m_n  = m;
    if (t + 1 < T_) {   // prefetch next step before the FMA block
      xq_n = *(const float4*)(xp + (size_t)(t + 1) * (B_ * 128));
      m_n  = mask[(size_t)(t + 1) * B_ + b];
    }

    float zi = xq.x, zf = xq.y, zg = xq.z, zo = xq.w;
#pragma unroll
    for (int f = 0; f < 32; ++f) {
      zi += hr[f] * Whr[f][0];
      zf += hr[f] * Whr[f][1];
      zg += hr[f] * Whr[f][2];
      zo += hr[f] * Whr[f][3];
    }
    const float ig = sigmf(zi);
    const float fg = sigmf(zf);
    const float gg = tanhf_(zg);
    const float og = sigmf(zo);
    const float cn = fg * cj + ig * gg;
    const float hn = og * tanhf_(cn);
    // masked update: keep previous state where m==0
    cj += m * (cn - cj);
    hj += m * (hn - hj);

    hs[half][j] = hj;
    __syncthreads();   // single-wave block: cheap; orders LDS write->read
#pragma unroll
    for (int q = 0; q < 8; ++q) {
      float4 v = *(const float4*)(&hs[half][q * 4]);
      hr[q * 4 + 0] = v.x; hr[q * 4 + 1] = v.y;
      hr[q * 4 + 2] = v.z; hr[q * 4 + 3] = v.w;
    }
    xq = xq_n; m = m_n;
  }

  // FC + softmax (every lane computes logits redundantly; lane j==0 writes)
  float logits[C_];
#pragma unroll
  for (int c = 0; c < C_; ++c) {
    float a = bfc[c];
#pragma unroll
    for (int f = 0; f < 32; ++f) a += hr[f] * Wfc[f * C_ + c];
    logits[c] = a;
  }
  if (j == 0) {
    float mx = logits[0];
#pragma unroll
    for (int c = 1; c < C_; ++c) mx = fmaxf(mx, logits[c]);
    float e[C_], s = 0.f;
#pragma unroll
    for (int c = 0; c < C_; ++c) { e[c] = __expf(logits[c] - mx); s += e[c]; }
    const float rs = 1.f / s;
#pragma unroll
    for (int c = 0; c < C_; ++c) out[(size_t)b * C_ + c] = e[c] * rs;
  }
}

// ---------------------------------------------------------------------------
extern "C" void kernel_launch(void* const* d_in, const int* in_sizes, int n_in,
                              void* d_out, int out_size, void* d_ws, size_t ws_size,
                              hipStream_t stream) {
  const float* x   = (const float*)d_in[0];
  const float* Wx  = (const float*)d_in[1];
  const float* Wh  = (const float*)d_in[2];
  const float* bv  = (const float*)d_in[3];
  const float* Wfc = (const float*)d_in[4];
  const float* bfc = (const float*)d_in[5];
  float* out = (float*)d_out;

  float* xz   = (float*)d_ws;                                 // T*B*128 f32 = 128 MB
  float* mask = (float*)((char*)d_ws + (size_t)T_ * B_ * 128 * 4);  // T*B f32 = 1 MB

  dim3 g1(B_ / 64, T_);
  k_xz<<<g1, 128, 0, stream>>>(x, Wx, bv, xz, mask);
  k_lstm<<<B_ / 2, 64, 0, stream>>>(xz, mask, Wh, Wfc, bfc, out);
}

// Round 4
// 286.292 us; speedup vs baseline: 1.7016x; 1.7016x over previous
//
#include <hip/hip_runtime.h>

#define B_ 512
#define T_ 512
#define F_ 128
#define H_ 32
#define C_ 6

typedef float f32x2 __attribute__((ext_vector_type(2)));

// ---------------------------------------------------------------------------
// Kernel 1: xz[row][c] = x[row,:] @ Wx[:,c] + bias[c],  row = b*T+t  (M=262144)
// Plain [b][t][128] output layout (row_out == row_in: no transpose anywhere).
// mask[row] = any(x[row,:] != 0).
// Block: 256 thr, tile 128 rows x 128 cols, K in 2 chunks of 64,
// reg-prefetch double buffer, LDS = 64 KB (2 blocks/CU), swizzled xl.
// ---------------------------------------------------------------------------
__global__ __launch_bounds__(256, 2) void k_xz(
    const float* __restrict__ x, const float* __restrict__ W,
    const float* __restrict__ bias, float* __restrict__ xz,
    float* __restrict__ mask)
{
  __shared__ float xl[128 * 64];   // 32 KB, XOR-swizzled rows
  __shared__ float wl[64 * 128];   // 32 KB, plain
  const int tid = threadIdx.x;
  const int m0  = blockIdx.x * 128;
  const int cg  = tid & 15;        // cols cg*4..+3 and 64+cg*4..+3
  const int rg  = tid >> 4;        // rows rg*8..+7

  float4 xpre[8], wpre[8];
  int rowbits = 0;

  auto load_chunk = [&](int ch) {
#pragma unroll
    for (int k = 0; k < 8; ++k) {
      const int u = tid + k * 256, r = u >> 4, q = u & 15;
      xpre[k] = *(const float4*)(x + (size_t)(m0 + r) * 128 + ch * 64 + q * 4);
    }
#pragma unroll
    for (int k = 0; k < 8; ++k) {
      const int u = tid + k * 256, f = u >> 5, q = u & 31;
      wpre[k] = *(const float4*)(W + (size_t)(ch * 64 + f) * 128 + q * 4);
    }
  };
  auto mask_chunk = [&]() {
#pragma unroll
    for (int k = 0; k < 8; ++k) {
      const float4 v = xpre[k];
      int nb = ((v.x != 0.f) || (v.y != 0.f) || (v.z != 0.f) || (v.w != 0.f)) ? 1 : 0;
      nb |= __shfl_xor(nb, 1); nb |= __shfl_xor(nb, 2);
      nb |= __shfl_xor(nb, 4); nb |= __shfl_xor(nb, 8);
      rowbits |= nb << k;
    }
  };
  auto write_chunk = [&]() {
#pragma unroll
    for (int k = 0; k < 8; ++k) {
      const int u = tid + k * 256, r = u >> 4, q = u & 15;
      *(float4*)(xl + r * 64 + ((q * 4) ^ (((r >> 3) & 3) << 2))) = xpre[k];
    }
#pragma unroll
    for (int k = 0; k < 8; ++k) {
      const int u = tid + k * 256, f = u >> 5, q = u & 31;
      *(float4*)(wl + f * 128 + q * 4) = wpre[k];
    }
  };

  float acc[8][8];
#pragma unroll
  for (int r = 0; r < 8; ++r)
#pragma unroll
    for (int u = 0; u < 8; ++u) acc[r][u] = 0.f;

  auto compute = [&]() {
#pragma unroll 2
    for (int fq = 0; fq < 16; ++fq) {
      float4 xv[8];
#pragma unroll
      for (int r = 0; r < 8; ++r)
        xv[r] = *(const float4*)(xl + (rg * 8 + r) * 64 + ((fq * 4) ^ ((rg & 3) << 2)));
#pragma unroll
      for (int ff = 0; ff < 4; ++ff) {
        const float* wr = wl + (fq * 4 + ff) * 128 + cg * 4;
        const float4 wa = *(const float4*)(wr);
        const float4 wb = *(const float4*)(wr + 64);
#pragma unroll
        for (int r = 0; r < 8; ++r) {
          const float xs = (ff == 0) ? xv[r].x : (ff == 1) ? xv[r].y
                         : (ff == 2) ? xv[r].z : xv[r].w;
          acc[r][0] += xs * wa.x;  acc[r][1] += xs * wa.y;
          acc[r][2] += xs * wa.z;  acc[r][3] += xs * wa.w;
          acc[r][4] += xs * wb.x;  acc[r][5] += xs * wb.y;
          acc[r][6] += xs * wb.z;  acc[r][7] += xs * wb.w;
        }
      }
    }
  };

  load_chunk(0);
  mask_chunk();
  write_chunk();
  __syncthreads();
  load_chunk(1);          // in flight during chunk-0 compute
  compute();
  __syncthreads();
  mask_chunk();
  write_chunk();
  __syncthreads();
  compute();

  // epilogue: bias + store (coalesced float4 pairs)
  float bb[8];
#pragma unroll
  for (int u = 0; u < 4; ++u) {
    bb[u]     = bias[cg * 4 + u];
    bb[4 + u] = bias[64 + cg * 4 + u];
  }
#pragma unroll
  for (int r = 0; r < 8; ++r) {
    float* op = xz + (size_t)(m0 + rg * 8 + r) * 128;
    float4 o0 = { acc[r][0] + bb[0], acc[r][1] + bb[1], acc[r][2] + bb[2], acc[r][3] + bb[3] };
    float4 o1 = { acc[r][4] + bb[4], acc[r][5] + bb[5], acc[r][6] + bb[6], acc[r][7] + bb[7] };
    *(float4*)(op + cg * 4)      = o0;
    *(float4*)(op + 64 + cg * 4) = o1;
  }
  if ((tid & 15) == 0) {
#pragma unroll
    for (int k = 0; k < 8; ++k)
      mask[m0 + k * 16 + rg] = (rowbits >> k) & 1 ? 1.f : 0.f;
  }
}

// ---------------------------------------------------------------------------
// Kernel 2: sequential LSTM scan + FC + softmax.  256 blocks x 64 threads.
// Wave = 2 batch rows; lane j owns gate col j of all 4 gates.
// Recurrent matvec via v_pk_fma_f32 (2 FMAs/inst). xz layout [b][t][128].
// ---------------------------------------------------------------------------
__device__ __forceinline__ float sigmf(float xx) {
  return __builtin_amdgcn_rcpf(1.f + __expf(-xx));
}
__device__ __forceinline__ float tanhf_(float xx) {
  return __builtin_amdgcn_rcpf(1.f + __expf(-2.f * xx)) * 2.f - 1.f;
}

__global__ __launch_bounds__(64) void k_lstm(
    const float* __restrict__ xz, const float* __restrict__ mask,
    const float* __restrict__ Wh, const float* __restrict__ Wfc,
    const float* __restrict__ bfc, float* __restrict__ out)
{
  const int lane = threadIdx.x;
  const int half = lane >> 5;
  const int j = lane & 31;
  const int b = blockIdx.x * 2 + half;

  // Wh packed in f-pairs: Whr[q][g] = (Wh[2q][g*32+j], Wh[2q+1][g*32+j])
  f32x2 Whr[16][4];
#pragma unroll
  for (int q = 0; q < 16; ++q)
#pragma unroll
    for (int g = 0; g < 4; ++g) {
      Whr[q][g][0] = Wh[(2 * q)     * 128 + g * 32 + j];
      Whr[q][g][1] = Wh[(2 * q + 1) * 128 + g * 32 + j];
    }

  f32x2 hr2[16];
#pragma unroll
  for (int q = 0; q < 16; ++q) { hr2[q][0] = 0.f; hr2[q][1] = 0.f; }
  float cj = 0.f, hj = 0.f;

  __shared__ __align__(16) float hs[2][32];

  const float* xp = xz + (size_t)b * (T_ * 128) + j;
  const float* mp = mask + (size_t)b * T_;

  float xg[4];
#pragma unroll
  for (int g = 0; g < 4; ++g) xg[g] = xp[g * 32];
  float m = mp[0];

  for (int t = 0; t < T_; ++t) {
    float xgn[4];
    float mn = m;
#pragma unroll
    for (int g = 0; g < 4; ++g) xgn[g] = xg[g];
    if (t + 1 < T_) {   // prefetch next step before the FMA block
#pragma unroll
      for (int g = 0; g < 4; ++g) xgn[g] = xp[(size_t)(t + 1) * 128 + g * 32];
      mn = mp[t + 1];
    }

    f32x2 a[4];
#pragma unroll
    for (int g = 0; g < 4; ++g) { a[g][0] = xg[g]; a[g][1] = 0.f; }
#pragma unroll
    for (int q = 0; q < 16; ++q) {
#pragma unroll
      for (int g = 0; g < 4; ++g)
        asm("v_pk_fma_f32 %0, %1, %2, %0" : "+v"(a[g]) : "v"(hr2[q]), "v"(Whr[q][g]));
    }
    const float zi = a[0][0] + a[0][1];
    const float zf = a[1][0] + a[1][1];
    const float zg = a[2][0] + a[2][1];
    const float zo = a[3][0] + a[3][1];

    const float ig = sigmf(zi);
    const float fg = sigmf(zf);
    const float gg = tanhf_(zg);
    const float og = sigmf(zo);
    const float cn = fg * cj + ig * gg;
    const float hn = og * tanhf_(cn);
    cj += m * (cn - cj);          // masked: keep previous state where m==0
    hj += m * (hn - hj);

    hs[half][j] = hj;
    __syncthreads();
#pragma unroll
    for (int q = 0; q < 8; ++q) {
      const float4 v = *(const float4*)(&hs[half][q * 4]);
      hr2[2 * q][0]     = v.x; hr2[2 * q][1]     = v.y;
      hr2[2 * q + 1][0] = v.z; hr2[2 * q + 1][1] = v.w;
    }
#pragma unroll
    for (int g = 0; g < 4; ++g) xg[g] = xgn[g];
    m = mn;
  }

  // FC + softmax (lane j==0 of each half writes)
  float hrs[32];
#pragma unroll
  for (int q = 0; q < 16; ++q) { hrs[2 * q] = hr2[q][0]; hrs[2 * q + 1] = hr2[q][1]; }
  float logits[C_];
#pragma unroll
  for (int c = 0; c < C_; ++c) {
    float aa = bfc[c];
#pragma unroll
    for (int f = 0; f < 32; ++f) aa += hrs[f] * Wfc[f * C_ + c];
    logits[c] = aa;
  }
  if (j == 0) {
    float mx = logits[0];
#pragma unroll
    for (int c = 1; c < C_; ++c) mx = fmaxf(mx, logits[c]);
    float e[C_], s = 0.f;
#pragma unroll
    for (int c = 0; c < C_; ++c) { e[c] = __expf(logits[c] - mx); s += e[c]; }
    const float rs = 1.f / s;
#pragma unroll
    for (int c = 0; c < C_; ++c) out[(size_t)b * C_ + c] = e[c] * rs;
  }
}

// ---------------------------------------------------------------------------
extern "C" void kernel_launch(void* const* d_in, const int* in_sizes, int n_in,
                              void* d_out, int out_size, void* d_ws, size_t ws_size,
                              hipStream_t stream) {
  const float* x   = (const float*)d_in[0];
  const float* Wx  = (const float*)d_in[1];
  const float* Wh  = (const float*)d_in[2];
  const float* bv  = (const float*)d_in[3];
  const float* Wfc = (const float*)d_in[4];
  const float* bfc = (const float*)d_in[5];
  float* out = (float*)d_out;

  float* xz   = (float*)d_ws;                                       // [B][T][128] f32 = 128 MB
  float* mask = (float*)((char*)d_ws + (size_t)B_ * T_ * 128 * 4);  // [B][T] f32 = 1 MB

  k_xz<<<(B_ * T_) / 128, 256, 0, stream>>>(x, Wx, bv, xz, mask);
  k_lstm<<<B_ / 2, 64, 0, stream>>>(xz, mask, Wh, Wfc, bfc, out);
}